// Round 10
// baseline (762.329 us; speedup 1.0000x reference)
//
#include <hip/hip_runtime.h>
#include <hip/hip_cooperative_groups.h>

#define N_NODES 100000
#define N_EDGES 800000
#define F_IN    75
#define HID     100
#define SP      128            // padded fp16 row stride (halves): 256 B = exactly 2 cache lines
#define XSTR    80             // fp16 row stride for converted input
#define NROWS   100096         // rows padded to multiple of 128
#define BN_EPS  1e-5f
#define LSTR    136            // LDS row stride (halves)
#define NBKT    256            // dst-range buckets
#define NPB     391            // nodes per bucket (256*391 >= 100000)
#define BIN_CAP 4096           // per-bucket global capacity (avg 3125)
#define SBCAP   24             // per-bucket LDS staging capacity in k_bin
#define CVTB    (NROWS * 10 / 256)  // 3910 cvt virtual blocks in prep phase
#define FTILES  (NROWS / 16)        // 6256 fused tiles per layer

typedef _Float16 h8 __attribute__((ext_vector_type(8)));
typedef float    f4 __attribute__((ext_vector_type(4)));

// ------------- binning: edges -> 256 dst-range buckets (coalesced appends) -----------

__global__ __launch_bounds__(256) void k_bin(const int* __restrict__ ei,
                                             int* __restrict__ bcur,
                                             int2* __restrict__ bkt) {
    __shared__ int2 sb[NBKT * SBCAP];               // 48 KB
    __shared__ int scur[NBKT], sbase[NBKT], spre[NBKT];
    int tid = threadIdx.x;
    scur[tid] = 0;
    __syncthreads();
    int base = blockIdx.x * 2048;
#pragma unroll
    for (int j = 0; j < 8; ++j) {
        int e = base + j * 256 + tid;
        if (e < N_EDGES) {
            int s = __builtin_nontemporal_load(&ei[e]);
            int d = __builtin_nontemporal_load(&ei[N_EDGES + e]);
            int b = d / NPB;
            int p = atomicAdd(&scur[b], 1);
            if (p < SBCAP) sb[b * SBCAP + p] = make_int2(s, d);
            else {                                  // rare overflow: direct append
                int gp = atomicAdd(&bcur[b], 1);
                bkt[(size_t)b * BIN_CAP + gp] = make_int2(s, d);
            }
        }
    }
    __syncthreads();
    {
        int c = scur[tid]; if (c > SBCAP) c = SBCAP;
        scur[tid] = c;
        sbase[tid] = atomicAdd(&bcur[tid], c);
        int lane = tid & 63;
        int x = c;
#pragma unroll
        for (int off = 1; off < 64; off <<= 1) {
            int y = __shfl_up(x, off);
            if (lane >= off) x += y;
        }
        spre[tid] = x;                              // per-wave inclusive
    }
    __syncthreads();
    {
        int add = 0;
        int wv = tid >> 6;
        for (int w2 = 0; w2 < wv; ++w2) add += spre[w2 * 64 + 63];
        __syncthreads();
        spre[tid] += add;
    }
    __syncthreads();
    int total = spre[NBKT - 1];
    for (int t = tid; t < total; t += 256) {
        int lo = 0, hi = NBKT - 1;
        while (lo < hi) { int mid = (lo + hi) >> 1; if (spre[mid] > t) hi = mid; else lo = mid + 1; }
        int bb = lo;
        int local = t - (spre[bb] - scur[bb]);
        bkt[(size_t)bb * BIN_CAP + sbase[bb] + local] = sb[bb * SBCAP + local];
    }
}

// ------------- per-bucket: LDS count + scan + rowp/dinv + csr scatter ---------------

__global__ __launch_bounds__(256) void k_local(const int* __restrict__ bcur,
                                               const int2* __restrict__ bkt,
                                               int* __restrict__ rowp,
                                               float* __restrict__ dinv,
                                               int* __restrict__ csr) {
    __shared__ int lcnt[512];                       // NPB=391, padded
    __shared__ int lofs[512];
    __shared__ int sbc[NBKT];
    __shared__ int swt[4];
    __shared__ int gbase_s;
    int b = blockIdx.x, tid = threadIdx.x;
    lcnt[tid] = 0; lcnt[256 + tid] = 0;
    sbc[tid] = bcur[tid];
    __syncthreads();
    if (tid == 0) { int s = 0; for (int j = 0; j < b; ++j) s += sbc[j]; gbase_s = s; }
    int cnt = sbc[b];
    const int2* bp = bkt + (size_t)b * BIN_CAP;
    int base_node = b * NPB;
    for (int i = tid; i < cnt; i += 256)
        atomicAdd(&lcnt[bp[i].y - base_node], 1);
    __syncthreads();
    int i0 = tid * 2;
    int c0 = lcnt[i0], c1 = lcnt[i0 + 1];
    int s = c0 + c1;
    int lane = tid & 63, wid = tid >> 6;
    int x = s;
#pragma unroll
    for (int off = 1; off < 64; off <<= 1) {
        int y = __shfl_up(x, off);
        if (lane >= off) x += y;
    }
    if (lane == 63) swt[wid] = x;
    __syncthreads();
    int woff = 0;
    for (int wv = 0; wv < wid; ++wv) woff += swt[wv];
    int excl = woff + x - s;
    lofs[i0] = excl;
    lofs[i0 + 1] = excl + c0;
    __syncthreads();
    int gbase = gbase_s;
    for (int i = tid; i < NPB; i += 256) {
        int node = base_node + i;
        if (node < N_NODES) {
            rowp[node] = gbase + lofs[i];
            dinv[node] = rsqrtf((float)(lcnt[i] + 1));
        }
    }
    if (b == NBKT - 1 && tid == 0) rowp[N_NODES] = N_EDGES;
    __syncthreads();
    for (int i = tid; i < cnt; i += 256) {
        int2 p = bp[i];
        int pos = atomicAdd(&lofs[p.y - base_node], 1);
        csr[gbase + pos] = p.x;
    }
}

// ---------------- argument bundle for the fused network ----------------

struct NetArgs {
    const float *x, *dinv;
    _Float16* xh;
    const float *W1, *W2, *W3, *fW1, *fW2;
    const float *b1, *g1, *be1, *m1, *v1;
    const float *b2, *g2, *be2, *m2, *v2;
    const float *b3, *g3, *be3, *m3, *v3;
    const float *fb1, *fg1, *fbe1, *fm1, *fv1;
    const float *fb2, *fg2, *fbe2, *fm2, *fv2;
    h8* wsw; float* bfold; float* aggp;
    const int *rowp, *csr;
    _Float16 *bufA, *bufB;
    const float *fW3, *fb3;
    float* out;
};

// -------- prep phase body: vb < CVTB: x -> fp16*dinv (stride 80);
// --------                  else: weight swizzle + param folding --------

__device__ void prep_body(int vb, const NetArgs& a, int tid) {
    if (vb < CVTB) {                                // ---- cvt part ----
        int id = vb * 256 + tid;
        int r = id / 10, c0 = (id - r * 10) * 8;
        h8 o;
#pragma unroll
        for (int j = 0; j < 8; ++j) o[j] = (_Float16)0.f;
        if (r < N_NODES) {
            float dv = a.dinv[r];
            const float* xr = a.x + (size_t)r * F_IN;
#pragma unroll
            for (int j = 0; j < 8; ++j) {
                int c = c0 + j;
                if (c < F_IN) o[j] = (_Float16)(__builtin_nontemporal_load(&xr[c]) * dv);
            }
        }
        *(h8*)&a.xh[(size_t)r * XSTR + c0] = o;
        return;
    }
    int sb = vb - CVTB;
    if (tid >= 128) return;
    int mat = sb >> 3, tile = sb & 7;

    if (mat == 5) {                       // agg params: tile 0,1,2 -> GCN layers 1,2,3
        if (tile > 2) return;
        const float *bb, *gg, *be, *mm, *vv;
        if (tile == 0) { bb = a.b1; gg = a.g1; be = a.be1; mm = a.m1; vv = a.v1; }
        else if (tile == 1) { bb = a.b2; gg = a.g2; be = a.be2; mm = a.m2; vv = a.v2; }
        else { bb = a.b3; gg = a.g3; be = a.be3; mm = a.m3; vv = a.v3; }
        int c = tid;
        float b = 0.f, s = 0.f, t = 0.f;
        if (c < HID) {
            b = bb[c];
            s = gg[c] * rsqrtf(vv[c] + BN_EPS);
            t = be[c] - mm[c] * s;
        }
        a.aggp[tile * 384 + c] = b;
        a.aggp[tile * 384 + 128 + c] = s;
        a.aggp[tile * 384 + 256 + c] = t;
        return;
    }

    const float* W; int K;
    const float *bb = nullptr, *gg = nullptr, *be = nullptr, *mm = nullptr, *vv = nullptr;
    bool fold = false;
    switch (mat) {
        case 0: W = a.W1; K = F_IN; break;
        case 1: W = a.W2; K = HID; break;
        case 2: W = a.W3; K = HID; break;
        case 3: W = a.fW1; K = HID; fold = true; bb = a.fb1; gg = a.fg1; be = a.fbe1; mm = a.fm1; vv = a.fv1; break;
        default: W = a.fW2; K = HID; fold = true; bb = a.fb2; gg = a.fg2; be = a.fbe2; mm = a.fm2; vv = a.fv2; break;
    }
    if (tid < 64) {
        int m16 = tid & 15, q = tid >> 4;
        int n = tile * 16 + m16;
        float sn = 1.f;
        if (fold && n < HID) sn = gg[n] * rsqrtf(vv[n] + BN_EPS);
        for (int kc = 0; kc < 4; ++kc) {
            h8 b;
#pragma unroll
            for (int j = 0; j < 8; ++j) {
                int k = kc * 32 + q * 8 + j;
                float v = (k < K && n < HID) ? W[k * HID + n] * sn : 0.f;
                b[j] = (_Float16)v;
            }
            a.wsw[((size_t)mat * 8 + tile) * 256 + kc * 64 + tid] = b;
        }
    }
    if (fold && tile == 0) {
        int c = tid;
        float v = 0.f;
        if (c < HID) {
            float s = gg[c] * rsqrtf(vv[c] + BN_EPS);
            float t = be[c] - mm[c] * s;
            v = bb[c] * s + t;
        }
        a.bfold[(mat - 3) * 128 + c] = v;
    }
}

// ================= fused building blocks (16 rows / tile, one node per 16-lane group) =================

// EPI 0: o = acc*dinv[n]; EPI 1: o = BN(relu(acc*dinv[n]+b)).
template <int ASTRIDE, int NCH_TOT, int NCH_ACT, int EPI>
__device__ __forceinline__ void gather16(
    const _Float16* __restrict__ src, const int* __restrict__ rowp,
    const int* __restrict__ csr, const float* __restrict__ dinv,
    const float* __restrict__ prm, _Float16* __restrict__ As,
    int rowbase, int tid) {
    const int g = tid >> 4, sub = tid & 15;
    if (sub >= NCH_TOT) return;                     // barriers live in the caller
    const int co = sub * 8;
    const int n = rowbase + g;
    float acc[8];
#pragma unroll
    for (int jj = 0; jj < 8; ++jj) acc[jj] = 0.f;
    float dv = 0.f;
    if ((NCH_ACT == 16 || sub < NCH_ACT) && n < N_NODES) {
        dv = dinv[n];
        {
            h8 v = *(const h8*)&src[(size_t)n * ASTRIDE + co];
#pragma unroll
            for (int jj = 0; jj < 8; ++jj) acc[jj] = (float)v[jj];
        }
        int beg = rowp[n], end = rowp[n + 1];
        int e = beg;
        for (; e + 7 < end; e += 8) {
            int s0 = csr[e],     s1 = csr[e + 1], s2 = csr[e + 2], s3 = csr[e + 3];
            int s4 = csr[e + 4], s5 = csr[e + 5], s6 = csr[e + 6], s7 = csr[e + 7];
            h8 v0 = *(const h8*)&src[(size_t)s0 * ASTRIDE + co];
            h8 v1 = *(const h8*)&src[(size_t)s1 * ASTRIDE + co];
            h8 v2 = *(const h8*)&src[(size_t)s2 * ASTRIDE + co];
            h8 v3 = *(const h8*)&src[(size_t)s3 * ASTRIDE + co];
            h8 v4 = *(const h8*)&src[(size_t)s4 * ASTRIDE + co];
            h8 v5 = *(const h8*)&src[(size_t)s5 * ASTRIDE + co];
            h8 v6 = *(const h8*)&src[(size_t)s6 * ASTRIDE + co];
            h8 v7 = *(const h8*)&src[(size_t)s7 * ASTRIDE + co];
#pragma unroll
            for (int jj = 0; jj < 8; ++jj)
                acc[jj] += (((float)v0[jj] + (float)v1[jj]) + ((float)v2[jj] + (float)v3[jj]))
                         + (((float)v4[jj] + (float)v5[jj]) + ((float)v6[jj] + (float)v7[jj]));
        }
        for (; e + 3 < end; e += 4) {
            int s0 = csr[e], s1 = csr[e + 1], s2 = csr[e + 2], s3 = csr[e + 3];
            h8 v0 = *(const h8*)&src[(size_t)s0 * ASTRIDE + co];
            h8 v1 = *(const h8*)&src[(size_t)s1 * ASTRIDE + co];
            h8 v2 = *(const h8*)&src[(size_t)s2 * ASTRIDE + co];
            h8 v3 = *(const h8*)&src[(size_t)s3 * ASTRIDE + co];
#pragma unroll
            for (int jj = 0; jj < 8; ++jj)
                acc[jj] += ((float)v0[jj] + (float)v1[jj]) + ((float)v2[jj] + (float)v3[jj]);
        }
        for (; e < end; ++e) {
            int s = csr[e];
            h8 v = *(const h8*)&src[(size_t)s * ASTRIDE + co];
#pragma unroll
            for (int jj = 0; jj < 8; ++jj) acc[jj] += (float)v[jj];
        }
    }
    h8 o;
    if constexpr (EPI == 0) {
#pragma unroll
        for (int jj = 0; jj < 8; ++jj) o[jj] = (_Float16)(acc[jj] * dv);
    } else {
        f4 bl0 = *(const f4*)&prm[co],       bl1 = *(const f4*)&prm[co + 4];
        f4 sl0 = *(const f4*)&prm[128 + co], sl1 = *(const f4*)&prm[128 + co + 4];
        f4 tl0 = *(const f4*)&prm[256 + co], tl1 = *(const f4*)&prm[256 + co + 4];
        o[0] = (_Float16)(fmaxf(acc[0] * dv + bl0[0], 0.f) * sl0[0] + tl0[0]);
        o[1] = (_Float16)(fmaxf(acc[1] * dv + bl0[1], 0.f) * sl0[1] + tl0[1]);
        o[2] = (_Float16)(fmaxf(acc[2] * dv + bl0[2], 0.f) * sl0[2] + tl0[2]);
        o[3] = (_Float16)(fmaxf(acc[3] * dv + bl0[3], 0.f) * sl0[3] + tl0[3]);
        o[4] = (_Float16)(fmaxf(acc[4] * dv + bl1[0], 0.f) * sl1[0] + tl1[0]);
        o[5] = (_Float16)(fmaxf(acc[5] * dv + bl1[1], 0.f) * sl1[1] + tl1[1]);
        o[6] = (_Float16)(fmaxf(acc[6] * dv + bl1[2], 0.f) * sl1[2] + tl1[2]);
        o[7] = (_Float16)(fmaxf(acc[7] * dv + bl1[3], 0.f) * sl1[3] + tl1[3]);
    }
    *(h8*)&As[g * LSTR + co] = o;
}

// 16x128 GEMM over the LDS tile: per wave, 2 n-tiles (cols w*16.. and +64), KC k-chunks
template <int KC>
__device__ __forceinline__ void mfma16(const _Float16* __restrict__ As,
                                       const h8* __restrict__ Bsw,
                                       int w, int l, int m16, int q, f4 (&acc)[2]) {
    h8 Bf[2][KC];
#pragma unroll
    for (int ti = 0; ti < 2; ++ti)
#pragma unroll
        for (int kc = 0; kc < KC; ++kc)
            Bf[ti][kc] = Bsw[((w + ti * 4) * 4 + kc) * 64 + l];
    acc[0] = (f4){0.f, 0.f, 0.f, 0.f};
    acc[1] = (f4){0.f, 0.f, 0.f, 0.f};
#pragma unroll
    for (int kc = 0; kc < KC; ++kc) {
        h8 a = *(const h8*)&As[m16 * LSTR + kc * 32 + q * 8];
        acc[0] = __builtin_amdgcn_mfma_f32_16x16x32_f16(a, Bf[0][kc], acc[0], 0, 0, 0);
        acc[1] = __builtin_amdgcn_mfma_f32_16x16x32_f16(a, Bf[1][kc], acc[1], 0, 0, 0);
    }
}

// ---------- layer 1+2 body: aggx(xh) -> GEMM W1' (+BN relu) -> GEMM W2' (xdinv) -> s2 ----------

__device__ void kf1_body(int vb, const NetArgs& a, _Float16* As, int tid) {
    const int w = tid >> 6, l = tid & 63;
    const int m16 = l & 15, q = l >> 4;
    const int rowbase = vb * 16;
    const int col0 = w * 16 + m16, col1 = col0 + 64;
    const h8* Bsw1 = a.wsw + 0 * 2048;
    const h8* Bsw2 = a.wsw + 1 * 2048;
    const float* prm0 = a.aggp;

    gather16<XSTR, 12, 10, 0>(a.xh, a.rowp, a.csr, a.dinv, nullptr, As, rowbase, tid);
    __syncthreads();

    f4 acc[2];
    __builtin_amdgcn_s_setprio(1);
    mfma16<3>(As, Bsw1, w, l, m16, q, acc);
    __builtin_amdgcn_s_setprio(0);
    __syncthreads();
    {   // relu(acc + b) * s + t  (BN1 folded) -> LDS (feeds GEMM2)
        float b0 = prm0[col0],       b1 = prm0[col1];
        float s0 = prm0[128 + col0], s1 = prm0[128 + col1];
        float t0 = prm0[256 + col0], t1 = prm0[256 + col1];
#pragma unroll
        for (int r = 0; r < 4; ++r) {
            int rl = q * 4 + r;
            As[rl * LSTR + col0] = (_Float16)(fmaxf(acc[0][r] + b0, 0.f) * s0 + t0);
            As[rl * LSTR + col1] = (_Float16)(fmaxf(acc[1][r] + b1, 0.f) * s1 + t1);
        }
    }
    __syncthreads();

    __builtin_amdgcn_s_setprio(1);
    mfma16<4>(As, Bsw2, w, l, m16, q, acc);
    __builtin_amdgcn_s_setprio(0);
    // direct register->global epilogue: x dinv[row]
#pragma unroll
    for (int r = 0; r < 4; ++r) {
        int row = rowbase + q * 4 + r;
        if (row < N_NODES) {
            float dv = a.dinv[row];
            a.bufA[(size_t)row * SP + col0] = (_Float16)(acc[0][r] * dv);
            a.bufA[(size_t)row * SP + col1] = (_Float16)(acc[1][r] * dv);
        }
    }
}

// ---------- layer 3 body: agg(s2)+BN -> GEMM W3' (xdinv) -> s3 ----------

__device__ void kf2_body(int vb, const NetArgs& a, _Float16* As, int tid) {
    const int w = tid >> 6, l = tid & 63;
    const int m16 = l & 15, q = l >> 4;
    const int rowbase = vb * 16;
    const int col0 = w * 16 + m16, col1 = col0 + 64;
    const h8* Bsw3 = a.wsw + 2 * 2048;
    const float* prm = a.aggp + 1 * 384;

    gather16<SP, 16, 16, 1>(a.bufA, a.rowp, a.csr, a.dinv, prm, As, rowbase, tid);
    __syncthreads();

    f4 acc[2];
    __builtin_amdgcn_s_setprio(1);
    mfma16<4>(As, Bsw3, w, l, m16, q, acc);
    __builtin_amdgcn_s_setprio(0);
#pragma unroll
    for (int r = 0; r < 4; ++r) {
        int row = rowbase + q * 4 + r;
        if (row < N_NODES) {
            float dv = a.dinv[row];
            a.bufB[(size_t)row * SP + col0] = (_Float16)(acc[0][r] * dv);
            a.bufB[(size_t)row * SP + col1] = (_Float16)(acc[1][r] * dv);
        }
    }
}

// ---------- head body: agg(s3)+BN -> dense head -> out ----------

__device__ void kf3_body(int vb, const NetArgs& a, _Float16* As, int tid) {
    const int w = tid >> 6, l = tid & 63;
    const int m16 = l & 15, q = l >> 4;
    const int rowbase = vb * 16;
    const int col0 = w * 16 + m16, col1 = col0 + 64;
    const h8* BswF1 = a.wsw + 3 * 2048;
    const h8* BswF2 = a.wsw + 4 * 2048;
    const float* prm = a.aggp + 2 * 384;
    const float* bfold1 = a.bfold;
    const float* bfold2 = a.bfold + 128;

    gather16<SP, 16, 16, 1>(a.bufB, a.rowp, a.csr, a.dinv, prm, As, rowbase, tid);
    __syncthreads();

    f4 acc[2];
    // ---- GEMM fW1' (BN folded) ----
    __builtin_amdgcn_s_setprio(1);
    mfma16<4>(As, BswF1, w, l, m16, q, acc);
    __builtin_amdgcn_s_setprio(0);
    __syncthreads();
    {
        float bf0 = bfold1[col0], bf1 = bfold1[col1];
#pragma unroll
        for (int r = 0; r < 4; ++r) {
            int rl = q * 4 + r;
            As[rl * LSTR + col0] = (_Float16)fmaxf(acc[0][r] + bf0, 0.f);
            As[rl * LSTR + col1] = (_Float16)fmaxf(acc[1][r] + bf1, 0.f);
        }
    }
    __syncthreads();

    // ---- GEMM fW2' (BN folded) ----
    __builtin_amdgcn_s_setprio(1);
    mfma16<4>(As, BswF2, w, l, m16, q, acc);
    __builtin_amdgcn_s_setprio(0);
    __syncthreads();
    {
        float bf0 = bfold2[col0], bf1 = bfold2[col1];
#pragma unroll
        for (int r = 0; r < 4; ++r) {
            int rl = q * 4 + r;
            As[rl * LSTR + col0] = (_Float16)fmaxf(acc[0][r] + bf0, 0.f);
            As[rl * LSTR + col1] = (_Float16)fmaxf(acc[1][r] + bf1, 0.f);
        }
    }
    __syncthreads();

    // ---- 100 -> 3: one row per 16-lane group + 16-lane shfl reduce ----
    {
        const int g = tid >> 4, sub = tid & 15;
        float p0 = 0.f, p1 = 0.f, p2 = 0.f;
        if (sub < 13) {
            h8 v = *(const h8*)&As[g * LSTR + sub * 8];
#pragma unroll
            for (int jj = 0; jj < 8; ++jj) {
                int c = sub * 8 + jj;
                if (c < HID) {
                    float av = (float)v[jj];
                    p0 = fmaf(av, a.fW3[c * 3 + 0], p0);
                    p1 = fmaf(av, a.fW3[c * 3 + 1], p1);
                    p2 = fmaf(av, a.fW3[c * 3 + 2], p2);
                }
            }
        }
#pragma unroll
        for (int mask = 1; mask < 16; mask <<= 1) {
            p0 += __shfl_xor(p0, mask);
            p1 += __shfl_xor(p1, mask);
            p2 += __shfl_xor(p2, mask);
        }
        if (sub == 0) {
            int grow = rowbase + g;
            if (grow < N_NODES) {
                a.out[grow * 3 + 0] = fmaxf(p0 + a.fb3[0], 0.f);
                a.out[grow * 3 + 1] = fmaxf(p1 + a.fb3[1], 0.f);
                a.out[grow * 3 + 2] = fmaxf(p2 + a.fb3[2], 0.f);
            }
        }
    }
}

// ---------------- cooperative fused network: prep -> L1+2 -> L3 -> head ----------------

__global__ __launch_bounds__(256) void k_net(NetArgs a) {
    cooperative_groups::grid_group grid = cooperative_groups::this_grid();
    __shared__ _Float16 As[16 * LSTR];
    const int tid = threadIdx.x;
    const int GB = gridDim.x;

    for (int vb = blockIdx.x; vb < CVTB + 48; vb += GB)
        prep_body(vb, a, tid);
    grid.sync();

    for (int vb = blockIdx.x; vb < FTILES; vb += GB) {
        kf1_body(vb, a, As, tid);
        __syncthreads();                            // As reuse across tiles
    }
    grid.sync();

    for (int vb = blockIdx.x; vb < FTILES; vb += GB) {
        kf2_body(vb, a, As, tid);
        __syncthreads();
    }
    grid.sync();

    for (int vb = blockIdx.x; vb < FTILES; vb += GB) {
        kf3_body(vb, a, As, tid);
        __syncthreads();
    }
}

// ---------------- non-cooperative fallback wrappers ----------------

__global__ __launch_bounds__(256) void k_prep_s(NetArgs a) {
    prep_body(blockIdx.x, a, threadIdx.x);
}
__global__ __launch_bounds__(256) void kf1_s(NetArgs a) {
    __shared__ _Float16 As[16 * LSTR];
    kf1_body(blockIdx.x, a, As, threadIdx.x);
}
__global__ __launch_bounds__(256) void kf2_s(NetArgs a) {
    __shared__ _Float16 As[16 * LSTR];
    kf2_body(blockIdx.x, a, As, threadIdx.x);
}
__global__ __launch_bounds__(256) void kf3_s(NetArgs a) {
    __shared__ _Float16 As[16 * LSTR];
    kf3_body(blockIdx.x, a, As, threadIdx.x);
}

// ---------------- launcher ----------------

extern "C" void kernel_launch(void* const* d_in, const int* in_sizes, int n_in,
                              void* d_out, int out_size, void* d_ws, size_t ws_size,
                              hipStream_t stream) {
    const float* x  = (const float*)d_in[0];
    const int*   ei = (const int*)d_in[1];

    char* w = (char*)d_ws;
    const size_t BUFS = (size_t)NROWS * SP * 2;         // 25,624,576 B
    _Float16* bufA = (_Float16*)(w);                    // s2 (stride 128)
    _Float16* bufB = (_Float16*)(w + BUFS);             // s3 (stride 128)
    _Float16* xh   = (_Float16*)(w + 2 * BUFS);         // 16,015,360 (stride 80)
    h8*    wsw   = (h8*)   (w + 67264512);              // 163,840
    float* bfold = (float*)(w + 67428352);              // 1,024
    float* aggp  = (float*)(w + 67429376);              // 4,608
    int*   bcur  = (int*)  (w + 67433984);              // 1,024
    int*   rowp  = (int*)  (w + 67435008);              // 400,128
    float* dinv  = (float*)(w + 67835136);              // 400,000
    int*   csr   = (int*)  (w + 68235136);              // 3,200,000
    int2*  bkt   = (int2*) (w + 71435136);              // 8,388,608 (end ~79.8 MB)

    NetArgs pa;
    pa.x = x; pa.dinv = dinv; pa.xh = xh;
    pa.W1 = (const float*)d_in[2];
    pa.b1 = (const float*)d_in[3];  pa.g1 = (const float*)d_in[4];
    pa.be1 = (const float*)d_in[5]; pa.m1 = (const float*)d_in[6];
    pa.v1 = (const float*)d_in[7];
    pa.W2 = (const float*)d_in[8];
    pa.b2 = (const float*)d_in[9];  pa.g2 = (const float*)d_in[10];
    pa.be2 = (const float*)d_in[11]; pa.m2 = (const float*)d_in[12];
    pa.v2 = (const float*)d_in[13];
    pa.W3 = (const float*)d_in[14];
    pa.b3 = (const float*)d_in[15]; pa.g3 = (const float*)d_in[16];
    pa.be3 = (const float*)d_in[17]; pa.m3 = (const float*)d_in[18];
    pa.v3 = (const float*)d_in[19];
    pa.fW1 = (const float*)d_in[20];
    pa.fb1 = (const float*)d_in[21]; pa.fg1 = (const float*)d_in[22];
    pa.fbe1 = (const float*)d_in[23]; pa.fm1 = (const float*)d_in[24];
    pa.fv1 = (const float*)d_in[25];
    pa.fW2 = (const float*)d_in[26];
    pa.fb2 = (const float*)d_in[27]; pa.fg2 = (const float*)d_in[28];
    pa.fbe2 = (const float*)d_in[29]; pa.fm2 = (const float*)d_in[30];
    pa.fv2 = (const float*)d_in[31];
    pa.fW3 = (const float*)d_in[32]; pa.fb3 = (const float*)d_in[33];
    pa.wsw = wsw; pa.bfold = bfold; pa.aggp = aggp;
    pa.rowp = rowp; pa.csr = csr;
    pa.bufA = bufA; pa.bufB = bufB;
    pa.out = (float*)d_out;

    (void)hipMemsetAsync(bcur, 0, NBKT * sizeof(int), stream);
    k_bin<<<(N_EDGES + 2047) / 2048, 256, 0, stream>>>(ei, bcur, bkt);
    k_local<<<NBKT, 256, 0, stream>>>(bcur, bkt, rowp, dinv, csr);

    // cooperative grid size: occupancy-validated, cached across calls
    static int coopG = 0;
    if (coopG == 0) {
        int occ = 0;
        if (hipOccupancyMaxActiveBlocksPerMultiprocessor(&occ, k_net, 256, 0) != hipSuccess || occ < 1)
            occ = 2;                                // conservative fallback
        int cus = 256;                              // MI355X default
        hipDeviceProp_t prop;
        int dev = 0;
        if (hipGetDevice(&dev) == hipSuccess &&
            hipGetDeviceProperties(&prop, dev) == hipSuccess &&
            prop.multiProcessorCount > 0)
            cus = prop.multiProcessorCount;
        long g = (long)occ * cus;
        if (g > FTILES) g = FTILES;
        coopG = (int)g;
    }

    void* kargs[] = { (void*)&pa };
    hipError_t ce = hipLaunchCooperativeKernel(k_net, dim3(coopG), dim3(256),
                                               kargs, 0, stream);
    if (ce != hipSuccess) {                         // fallback: separate dispatches
        k_prep_s<<<CVTB + 48, 256, 0, stream>>>(pa);
        kf1_s<<<FTILES, 256, 0, stream>>>(pa);
        kf2_s<<<FTILES, 256, 0, stream>>>(pa);
        kf3_s<<<FTILES, 256, 0, stream>>>(pa);
    }
}